// Round 10
// baseline (275.234 us; speedup 1.0000x reference)
//
#include <hip/hip_runtime.h>
#include <stdint.h>
#include <math.h>

// BSRBF-KAN layer, SPLIT pipeline (round 10):
// out = relu(LN(x)) @ base_W^T + (bspline+rbf)(LN(x)) @ spline_W^T
//  * prep: unchanged (wprep + LN + relu + basis -> A f16).
//  * gemm: round-9's counted-vmcnt pipeline was ~87% LDS-port-bound
//    (176 KB/tile/CU).  Round-10 moves A-fragment reads OFF the LDS port:
//    A frags are loaded DIRECTLY from global (L2-resident: XCD-chunked
//    remap keeps each 2.36 MB A panel on one XCD) into ping/pong register
//    sets, prefetched one K-tile ahead.  B stays in LDS (written once via
//    global_load_lds, re-read 4x).  LDS/tile: 176 -> 80 KB; A traffic
//    rides the parallel VMEM/L2 pipe.  LDS = 48 KB (B triple-buffer).
//    vmcnt ledger: steady body issues 8 A-loads + 2 B-GLLs; barrier wait
//    vmcnt(10) drains exactly B(t+1); max 20 outstanding.
//   ws: [W: 512*4608 f16][A: 16384*4608 f16]

#define D_IN  512
#define D_OUT 512
#define NB    8
#define KTOT  (D_IN + D_IN * NB)   // 4608
#define ROWS  16384
#define NT    (KTOT / 64)          // 72

typedef __attribute__((ext_vector_type(2))) _Float16 f16x2;
typedef __attribute__((ext_vector_type(8))) _Float16 f16x8;
typedef __attribute__((ext_vector_type(4))) float f32x4;

__device__ __forceinline__ short f2h(float f) {
  return (short)__builtin_bit_cast(unsigned short, (_Float16)f);  // RNE
}
__device__ __forceinline__ unsigned pkrtz_u(float a, float b) {
  return __builtin_bit_cast(unsigned, __builtin_amdgcn_cvt_pkrtz(a, b));
}
__device__ __forceinline__ unsigned pkadd_f16(unsigned a, unsigned b) {
  f16x2 x = __builtin_bit_cast(f16x2, a), y = __builtin_bit_cast(f16x2, b);
  f16x2 r = x + y;
  return __builtin_bit_cast(unsigned, r);
}

// ---------------- basis eval: one d -> 8 packed f16 (spline + rbf) -------
// (verified rounds 3-9) Spline via 14-entry perm-selector LUT; RBF via
// 3-transcendental cascade; z clamped to [-8,16].
__device__ __forceinline__ void basis_write(float xn, const uint4* lut,
                                            short* dst) {
  const float u = fmaf(xn, 1.66666667f, 5.5f);  // (xn+3.3)/0.6
  const float cf = floorf(u);
  const int c = (int)cf;
  const float t = u - cf;
  const float t2 = t * t, t3 = t2 * t, omt = 1.0f - t;
  const float v0 = t3 * 0.16666667f;
  const float v1 = fmaf(fmaf(fmaf(t, -0.5f, 0.5f), t, 0.5f), t, 0.16666667f);
  const float v2 = fmaf(t3, 0.5f, fmaf(t2, -1.0f, 0.66666667f));
  const float v3 = omt * omt * (omt * 0.16666667f);
  const unsigned va = pkrtz_u(v0, v1);
  const unsigned vb = pkrtz_u(v2, v3);

  float z = fmaf(xn, 2.80261895f, 4.20392842f);
  z = fminf(fmaxf(z, -8.0f), 16.0f);
  const float d3 = z - 3.60336723f;              // 3*DLT
  const float R3 = __builtin_amdgcn_exp2f(-(d3 * d3));
  const float G  = __builtin_amdgcn_exp2f(z * 2.40224482f);  // 2*DLT
  const float Gi = __builtin_amdgcn_rcpf(G);
  const float R4 = R3 * (G * 9.11881966e-4f);    // e^-7
  const float R5 = R4 * (G * 1.23409804e-4f);    // e^-9
  const float R6 = R5 * (G * 1.67017007e-5f);    // e^-11
  const float R7 = R6 * (G * 2.26032941e-6f);    // e^-13
  const float R2 = R3 * (Gi * 148.413159f);      // e^5
  const float R1 = R2 * (Gi * 20.0855369f);      // e^3
  const float R0 = R1 * (Gi * 2.71828183f);      // e^1

  const int idx = (c < -1 ? -1 : (c > 12 ? 12 : c)) + 1;
  const uint4 sel = lut[idx];
  const unsigned w0 = pkadd_f16(__builtin_amdgcn_perm(vb, va, sel.x), pkrtz_u(R0, R1));
  const unsigned w1 = pkadd_f16(__builtin_amdgcn_perm(vb, va, sel.y), pkrtz_u(R2, R3));
  const unsigned w2 = pkadd_f16(__builtin_amdgcn_perm(vb, va, sel.z), pkrtz_u(R4, R5));
  const unsigned w3 = pkadd_f16(__builtin_amdgcn_perm(vb, va, sel.w), pkrtz_u(R6, R7));
  const uint4 v4 = {w0, w1, w2, w3};
  *(uint4*)dst = v4;  // 16B store (coalesced 1KB/wave across lanes)
}

// ---------------- prep: wprep + LN + relu + basis -> A[ROWS][KTOT] -------
__global__ __launch_bounds__(256) void prep_kernel(
    const float* __restrict__ x, const float* __restrict__ gamma,
    const float* __restrict__ beta, const float* __restrict__ bw,
    const float* __restrict__ sw, short* __restrict__ A,
    short* __restrict__ W) {
  if (blockIdx.x >= ROWS / 4) {
    const int o = blockIdx.x - ROWS / 4;
    for (int k = threadIdx.x; k < KTOT; k += 256) {
      const float v = (k < D_IN) ? bw[o * D_IN + k]
                                 : sw[(size_t)o * (D_IN * NB) + (k - D_IN)];
      W[(size_t)o * KTOT + k] = f2h(v);
    }
    return;
  }
  __shared__ uint4 LUT[14];
  const int tid = threadIdx.x;
  if (tid < 14) {
    const int cc = tid - 1;
    unsigned e[4];
#pragma unroll
    for (int h = 0; h < 4; ++h) {
      const int m = cc - 2 * h, m2 = m - 1;
      const unsigned lo =
          (m >= 0 && m <= 3) ? (unsigned)((2 * m) | ((2 * m + 1) << 8)) : 0x0C0Cu;
      const unsigned hi =
          (m2 >= 0 && m2 <= 3) ? (unsigned)((2 * m2) | ((2 * m2 + 1) << 8)) : 0x0C0Cu;
      e[h] = lo | (hi << 16);
    }
    const uint4 ev = {e[0], e[1], e[2], e[3]};
    LUT[tid] = ev;
  }
  __syncthreads();

  const int lane = tid & 63, wave = tid >> 6;
  const int row = blockIdx.x * 4 + wave;
  const float* xr = x + (size_t)row * D_IN;

  float xv[8];
  float s = 0.0f, ss = 0.0f;
#pragma unroll
  for (int e = 0; e < 8; e++) {
    xv[e] = xr[e * 64 + lane];
    s += xv[e];
    ss += xv[e] * xv[e];
  }
#pragma unroll
  for (int off = 32; off > 0; off >>= 1) {
    s += __shfl_xor(s, off);
    ss += __shfl_xor(ss, off);
  }
  const float mu = s * (1.0f / D_IN);
  const float var = ss * (1.0f / D_IN) - mu * mu;
  const float rstd = 1.0f / sqrtf(var + 1e-5f);

  short* Ar = A + (size_t)row * KTOT;
#pragma unroll
  for (int e = 0; e < 8; e++) {
    const int d = e * 64 + lane;
    const float xn = fmaf((xv[e] - mu) * rstd, gamma[d], beta[d]);
    Ar[d] = f2h(fmaxf(xn, 0.0f));
    basis_write(xn, LUT, &Ar[D_IN + d * NB]);
  }
}

// ---------------- f16 MFMA GEMM: A-from-L2 regs + B-in-LDS pipeline ------
#define GLL(g, l)                                               \
  __builtin_amdgcn_global_load_lds(                             \
      (const __attribute__((address_space(1))) void*)(g),       \
      (__attribute__((address_space(3))) void*)(l), 16, 0, 0)

__global__ __launch_bounds__(512, 1) void gemm_kernel(
    const short* __restrict__ A, const short* __restrict__ W,
    float* __restrict__ out) {
  __shared__ short Bb[3 * 128 * 64];  // 48 KB, B triple-buffer
  const int tid = threadIdx.x;                 // 512
  const int lane = tid & 63, wave = tid >> 6;  // 8 waves

  // XCD-chunked remap (bijective, 256 = 8*32): XCD x runs wg in [32x,32x+32)
  // = m-panels 8x..8x+7 with all 4 n-blocks -> A panel L2-resident per XCD.
  const int b = blockIdx.x;
  const int wg = (b & 7) * 32 + (b >> 3);
  const int m0 = (wg >> 2) * 256;
  const int n0 = (wg & 3) * 128;
  const int wm = wave >> 1, wn = wave & 1;  // per-wave 64x64 output

  const f32x4 zero = {0.0f, 0.0f, 0.0f, 0.0f};
  f32x4 acc[4][4];
#pragma unroll
  for (int i = 0; i < 4; i++)
#pragma unroll
    for (int j = 0; j < 4; j++) acc[i][j] = zero;

  // B staging map (R7/R9-verified): thread -> (row r0 = tid>>3 in 0..63,
  // chunk-slot c0 = tid&7); call 1 adds +64 rows; src chunk = c0 ^ (r0&7).
  const int r0 = tid >> 3;
  const int c0 = tid & 7;
  const int qsrc = c0 ^ (r0 & 7);
  const short* gB = W + (size_t)(n0 + r0) * KTOT + qsrc * 8;
  const int lbase = wave * 512;  // wave-uniform dest base; HW adds lane*16B

  const int lr = lane & 15;
  const int q = lane >> 4;
  const int x7 = lr & 7;

  // A-fragment direct-load base: row = m0 + wm*64 + mi*16 + lr, chunk kk2*4+q.
  // Same bytes the swizzled LDS slot held -> layout-safe.
  const short* gAf = A + (size_t)(m0 + wm * 64 + lr) * KTOT + q * 8;

  short* B0p = Bb;  short* B1p = Bb + 8192;  short* B2p = Bb + 16384;

#define STAGE_B(Bd, kt)                                                \
  do {                                                                 \
    GLL(gB + (kt), (Bd) + lbase);                                      \
    GLL(gB + (size_t)64 * KTOT + (kt), (Bd) + 4096 + lbase);           \
  } while (0)

  // 8 global_load_dwordx4 into a named ping/pong frag set (rule #20: all
  // indices compile-time).
#define LOAD_A(dst, kt)                                                        \
  do {                                                                         \
    _Pragma("unroll")                                                          \
    for (int kk2 = 0; kk2 < 2; kk2++)                                          \
      _Pragma("unroll")                                                        \
      for (int mi = 0; mi < 4; mi++)                                           \
        dst[kk2][mi] = *(const f16x8*)(gAf + (size_t)mi * 16 * KTOT + (kt) +   \
                                       kk2 * 32);                              \
  } while (0)

  f16x8 aP[2][4], aQ[2][4], bf[2][4];
#define READ_BF(Bc)                                                            \
  do {                                                                         \
    _Pragma("unroll")                                                          \
    for (int kk2 = 0; kk2 < 2; kk2++) {                                        \
      const int off = ((kk2 * 4 + q) ^ x7) * 8;                                \
      _Pragma("unroll")                                                        \
      for (int nj = 0; nj < 4; nj++)                                           \
        bf[kk2][nj] = *(const f16x8*)&(Bc)[(wn * 64 + nj * 16 + lr) * 64 + off]; \
    }                                                                          \
  } while (0)

#define MFMA_T(asrc)                                                           \
  do {                                                                         \
    __builtin_amdgcn_s_setprio(1);                                             \
    _Pragma("unroll")                                                          \
    for (int kk2 = 0; kk2 < 2; kk2++)                                          \
      _Pragma("unroll")                                                        \
      for (int mi = 0; mi < 4; mi++)                                           \
        _Pragma("unroll")                                                      \
        for (int nj = 0; nj < 4; nj++)                                         \
          acc[mi][nj] = __builtin_amdgcn_mfma_f32_16x16x32_f16(                \
              asrc[kk2][mi], bf[kk2][nj], acc[mi][nj], 0, 0, 0);               \
    __builtin_amdgcn_s_setprio(0);                                             \
  } while (0)

  // half-iter body: consume 'cur' A-regs on tile t; prefetch A(t+1) into
  // 'nxt'; stage B(t+2); barrier with vmcnt(10) (drains B(t+1), keeps
  // A(t+1)+B(t+2) in flight); rotate B buffers.
#define HALF(t, cur, nxt)                                                      \
  do {                                                                         \
    READ_BF(cB);                                                               \
    LOAD_A(nxt, ((t) + 1) * 64);                                               \
    STAGE_B(sB, ((t) + 2) * 64);                                               \
    MFMA_T(cur);                                                               \
    __builtin_amdgcn_sched_barrier(0);                                         \
    asm volatile("s_waitcnt vmcnt(10)" ::: "memory");                          \
    __builtin_amdgcn_s_barrier();                                              \
    __builtin_amdgcn_sched_barrier(0);                                         \
    short* tp = cB; cB = nB; nB = sB; sB = tp;                                 \
  } while (0)

  // prologue: A(0)->aP, B(0)->B0, B(1)->B1; vmcnt(2) keeps B(1) in flight.
  LOAD_A(aP, 0);
  STAGE_B(B0p, 0);
  STAGE_B(B1p, 64);
  __builtin_amdgcn_sched_barrier(0);
  asm volatile("s_waitcnt vmcnt(2)" ::: "memory");
  __builtin_amdgcn_s_barrier();
  __builtin_amdgcn_sched_barrier(0);

  short* cB = B0p; short* nB = B1p; short* sB = B2p;

  // steady: t = 0..69 (35 pairs); last staged B is t=69 -> B(71) in-range.
  for (int tt = 0; tt < 70; tt += 2) {
    HALF(tt, aP, aQ);
    HALF(tt + 1, aQ, aP);
  }

  // t = 70: consume aP, prefetch A(71), no B staging; vmcnt(8) drains B(71).
  READ_BF(cB);
  LOAD_A(aQ, 71 * 64);
  MFMA_T(aP);
  __builtin_amdgcn_sched_barrier(0);
  asm volatile("s_waitcnt vmcnt(8)" ::: "memory");
  __builtin_amdgcn_s_barrier();
  __builtin_amdgcn_sched_barrier(0);
  cB = nB;

  // t = 71: final tile (compiler waits for aQ regs + bf lgkm).
  READ_BF(cB);
  MFMA_T(aQ);

#undef HALF
#undef MFMA_T
#undef READ_BF
#undef LOAD_A
#undef STAGE_B

  // C/D layout (m89-verified): col = lane&15, row = (lane>>4)*4 + reg
#pragma unroll
  for (int mi = 0; mi < 4; mi++) {
#pragma unroll
    for (int nj = 0; nj < 4; nj++) {
      const int gcol = n0 + wn * 64 + nj * 16 + lr;
#pragma unroll
      for (int r = 0; r < 4; r++) {
        const int grow = m0 + wm * 64 + mi * 16 + q * 4 + r;
        out[(size_t)grow * D_OUT + gcol] = acc[mi][nj][r];
      }
    }
  }
}

extern "C" void kernel_launch(void* const* d_in, const int* in_sizes, int n_in,
                              void* d_out, int out_size, void* d_ws, size_t ws_size,
                              hipStream_t stream) {
  const float* x     = (const float*)d_in[0];
  const float* gamma = (const float*)d_in[1];
  const float* beta  = (const float*)d_in[2];
  const float* bw    = (const float*)d_in[3];
  const float* sw    = (const float*)d_in[4];
  float* out = (float*)d_out;

  short* W = (short*)d_ws;                         // 512 * 4608 f16
  short* A = (short*)d_ws + (size_t)D_OUT * KTOT;  // 16384 * 4608 f16

  prep_kernel<<<ROWS / 4 + D_OUT, 256, 0, stream>>>(x, gamma, beta, bw, sw, A, W);
  gemm_kernel<<<256, 512, 0, stream>>>(A, W, out);
}

// Round 11
// 214.586 us; speedup vs baseline: 1.2826x; 1.2826x over previous
//
#include <hip/hip_runtime.h>
#include <stdint.h>
#include <math.h>

// BSRBF-KAN layer, SPLIT pipeline (round 11):
// out = relu(LN(x)) @ base_W^T + (bspline+rbf)(LN(x)) @ spline_W^T
//  * prep: unchanged (wprep + LN + relu + basis -> A f16).  ~42 us.
//  * gemm: r9's counted-vmcnt triple-buffer pipeline (71 us, LDS-port-bound:
//    176 KB/tile/CU) with ONE change: 4 waves x (128x64) wave-tiles instead
//    of 8 x (64x64).  Per-wave LDS read volume = (Mw+Nw)*64*2B, so the
//    bigger tile cuts re-reads: A x2 + B x2 -> 144 KB/tile (-18%), floor
//    62 -> ~51 us.  1 wave/SIMD is acceptable: LDS (144 KB) already forces
//    1 block/CU, the wave has 24 independent ds_reads + 64 independent-chain
//    MFMAs of ILP, and launch_bounds(256,1) lifts the VGPR cap (acc[8][4]
//    =128 + frags 96 ~ 230 regs, no spill risk at 1 wave/SIMD).
//    vmcnt ledger: 12 GLLs/tile (A 8 + B 4); steady barrier wait vmcnt(12)
//    drains exactly t+1's loads, keeps t+2's 12 in flight (T4).
//    r10's A-direct-from-L2 regression (71->174) confirmed staged-LDS A.
//   ws: [W: 512*4608 f16][A: 16384*4608 f16]

#define D_IN  512
#define D_OUT 512
#define NB    8
#define KTOT  (D_IN + D_IN * NB)   // 4608
#define ROWS  16384
#define NT    (KTOT / 64)          // 72

typedef __attribute__((ext_vector_type(2))) _Float16 f16x2;
typedef __attribute__((ext_vector_type(8))) _Float16 f16x8;
typedef __attribute__((ext_vector_type(4))) float f32x4;

__device__ __forceinline__ short f2h(float f) {
  return (short)__builtin_bit_cast(unsigned short, (_Float16)f);  // RNE
}
__device__ __forceinline__ unsigned pkrtz_u(float a, float b) {
  return __builtin_bit_cast(unsigned, __builtin_amdgcn_cvt_pkrtz(a, b));
}
__device__ __forceinline__ unsigned pkadd_f16(unsigned a, unsigned b) {
  f16x2 x = __builtin_bit_cast(f16x2, a), y = __builtin_bit_cast(f16x2, b);
  f16x2 r = x + y;
  return __builtin_bit_cast(unsigned, r);
}

// ---------------- basis eval: one d -> 8 packed f16 (spline + rbf) -------
// (verified rounds 3-10) Spline via 14-entry perm-selector LUT; RBF via
// 3-transcendental cascade; z clamped to [-8,16].
__device__ __forceinline__ void basis_write(float xn, const uint4* lut,
                                            short* dst) {
  const float u = fmaf(xn, 1.66666667f, 5.5f);  // (xn+3.3)/0.6
  const float cf = floorf(u);
  const int c = (int)cf;
  const float t = u - cf;
  const float t2 = t * t, t3 = t2 * t, omt = 1.0f - t;
  const float v0 = t3 * 0.16666667f;
  const float v1 = fmaf(fmaf(fmaf(t, -0.5f, 0.5f), t, 0.5f), t, 0.16666667f);
  const float v2 = fmaf(t3, 0.5f, fmaf(t2, -1.0f, 0.66666667f));
  const float v3 = omt * omt * (omt * 0.16666667f);
  const unsigned va = pkrtz_u(v0, v1);
  const unsigned vb = pkrtz_u(v2, v3);

  float z = fmaf(xn, 2.80261895f, 4.20392842f);
  z = fminf(fmaxf(z, -8.0f), 16.0f);
  const float d3 = z - 3.60336723f;              // 3*DLT
  const float R3 = __builtin_amdgcn_exp2f(-(d3 * d3));
  const float G  = __builtin_amdgcn_exp2f(z * 2.40224482f);  // 2*DLT
  const float Gi = __builtin_amdgcn_rcpf(G);
  const float R4 = R3 * (G * 9.11881966e-4f);    // e^-7
  const float R5 = R4 * (G * 1.23409804e-4f);    // e^-9
  const float R6 = R5 * (G * 1.67017007e-5f);    // e^-11
  const float R7 = R6 * (G * 2.26032941e-6f);    // e^-13
  const float R2 = R3 * (Gi * 148.413159f);      // e^5
  const float R1 = R2 * (Gi * 20.0855369f);      // e^3
  const float R0 = R1 * (Gi * 2.71828183f);      // e^1

  const int idx = (c < -1 ? -1 : (c > 12 ? 12 : c)) + 1;
  const uint4 sel = lut[idx];
  const unsigned w0 = pkadd_f16(__builtin_amdgcn_perm(vb, va, sel.x), pkrtz_u(R0, R1));
  const unsigned w1 = pkadd_f16(__builtin_amdgcn_perm(vb, va, sel.y), pkrtz_u(R2, R3));
  const unsigned w2 = pkadd_f16(__builtin_amdgcn_perm(vb, va, sel.z), pkrtz_u(R4, R5));
  const unsigned w3 = pkadd_f16(__builtin_amdgcn_perm(vb, va, sel.w), pkrtz_u(R6, R7));
  const uint4 v4 = {w0, w1, w2, w3};
  *(uint4*)dst = v4;  // 16B store (coalesced 1KB/wave across lanes)
}

// ---------------- prep: wprep + LN + relu + basis -> A[ROWS][KTOT] -------
__global__ __launch_bounds__(256) void prep_kernel(
    const float* __restrict__ x, const float* __restrict__ gamma,
    const float* __restrict__ beta, const float* __restrict__ bw,
    const float* __restrict__ sw, short* __restrict__ A,
    short* __restrict__ W) {
  if (blockIdx.x >= ROWS / 4) {
    const int o = blockIdx.x - ROWS / 4;
    for (int k = threadIdx.x; k < KTOT; k += 256) {
      const float v = (k < D_IN) ? bw[o * D_IN + k]
                                 : sw[(size_t)o * (D_IN * NB) + (k - D_IN)];
      W[(size_t)o * KTOT + k] = f2h(v);
    }
    return;
  }
  __shared__ uint4 LUT[14];
  const int tid = threadIdx.x;
  if (tid < 14) {
    const int cc = tid - 1;
    unsigned e[4];
#pragma unroll
    for (int h = 0; h < 4; ++h) {
      const int m = cc - 2 * h, m2 = m - 1;
      const unsigned lo =
          (m >= 0 && m <= 3) ? (unsigned)((2 * m) | ((2 * m + 1) << 8)) : 0x0C0Cu;
      const unsigned hi =
          (m2 >= 0 && m2 <= 3) ? (unsigned)((2 * m2) | ((2 * m2 + 1) << 8)) : 0x0C0Cu;
      e[h] = lo | (hi << 16);
    }
    const uint4 ev = {e[0], e[1], e[2], e[3]};
    LUT[tid] = ev;
  }
  __syncthreads();

  const int lane = tid & 63, wave = tid >> 6;
  const int row = blockIdx.x * 4 + wave;
  const float* xr = x + (size_t)row * D_IN;

  float xv[8];
  float s = 0.0f, ss = 0.0f;
#pragma unroll
  for (int e = 0; e < 8; e++) {
    xv[e] = xr[e * 64 + lane];
    s += xv[e];
    ss += xv[e] * xv[e];
  }
#pragma unroll
  for (int off = 32; off > 0; off >>= 1) {
    s += __shfl_xor(s, off);
    ss += __shfl_xor(ss, off);
  }
  const float mu = s * (1.0f / D_IN);
  const float var = ss * (1.0f / D_IN) - mu * mu;
  const float rstd = 1.0f / sqrtf(var + 1e-5f);

  short* Ar = A + (size_t)row * KTOT;
#pragma unroll
  for (int e = 0; e < 8; e++) {
    const int d = e * 64 + lane;
    const float xn = fmaf((xv[e] - mu) * rstd, gamma[d], beta[d]);
    Ar[d] = f2h(fmaxf(xn, 0.0f));
    basis_write(xn, LUT, &Ar[D_IN + d * NB]);
  }
}

// ---------------- f16 MFMA GEMM: 4-wave 128x64 tiles, counted vmcnt ------
#define GLL(g, l)                                               \
  __builtin_amdgcn_global_load_lds(                             \
      (const __attribute__((address_space(1))) void*)(g),       \
      (__attribute__((address_space(3))) void*)(l), 16, 0, 0)

__global__ __launch_bounds__(256, 1) void gemm_kernel(
    const short* __restrict__ A, const short* __restrict__ W,
    float* __restrict__ out) {
  __shared__ short Ab[3 * 256 * 64];  // 96 KB, A triple-buffer
  __shared__ short Bb[3 * 128 * 64];  // 48 KB, B triple-buffer
  const int tid = threadIdx.x;                 // 256
  const int lane = tid & 63, wave = tid >> 6;  // 4 waves

  // XCD-chunked remap (bijective, 256 = 8*32): XCD x runs wg in [32x,32x+32)
  // = m-panels 8x..8x+7 with all 4 n-blocks -> A panel read by ONE XCD.
  const int b = blockIdx.x;
  const int wg = (b & 7) * 32 + (b >> 3);
  const int m0 = (wg >> 2) * 256;
  const int n0 = (wg & 3) * 128;
  const int wm = wave >> 1, wn = wave & 1;  // per-wave 128x64 output

  const f32x4 zero = {0.0f, 0.0f, 0.0f, 0.0f};
  f32x4 acc[8][4];
#pragma unroll
  for (int i = 0; i < 8; i++)
#pragma unroll
    for (int j = 0; j < 4; j++) acc[i][j] = zero;

  // staging map: thread -> (row r0 = tid>>3 in 0..31, chunk-slot c0 = tid&7);
  // calls add +32 rows; src chunk = c0 ^ (r0&7) (row&7 == r0&7: +32 rows
  // preserves low 3 bits).  Coalesced 128B segments.
  const int r0 = tid >> 3;
  const int c0 = tid & 7;
  const int qsrc = c0 ^ (r0 & 7);
  const short* gA = A + (size_t)(m0 + r0) * KTOT + qsrc * 8;
  const short* gB = W + (size_t)(n0 + r0) * KTOT + qsrc * 8;
  const int wv512 = wave * 512;  // wave-uniform dest base; HW adds lane*16B

  const int lr = lane & 15;
  const int q = lane >> 4;
  const int x7 = lr & 7;

  short* A0p = Ab;  short* A1p = Ab + 16384;  short* A2p = Ab + 32768;
  short* B0p = Bb;  short* B1p = Bb + 8192;   short* B2p = Bb + 16384;

  // 12 GLLs per tile: A rows 0..255 (8 calls of 32 rows), B rows 0..127 (4).
#define GLLA(j, Ad, kt) \
  GLL(gA + (size_t)(32 * (j)) * KTOT + (kt), (Ad) + (j) * 2048 + wv512)
#define GLLB(j, Bd, kt) \
  GLL(gB + (size_t)(32 * (j)) * KTOT + (kt), (Bd) + (j) * 2048 + wv512)
#define STAGE_H1(Ad, Bd, kt)                                           \
  do {                                                                 \
    GLLA(0, Ad, kt); GLLA(1, Ad, kt); GLLA(2, Ad, kt); GLLA(3, Ad, kt);\
    GLLB(0, Bd, kt); GLLB(1, Bd, kt);                                  \
  } while (0)
#define STAGE_H2(Ad, Bd, kt)                                           \
  do {                                                                 \
    GLLA(4, Ad, kt); GLLA(5, Ad, kt); GLLA(6, Ad, kt); GLLA(7, Ad, kt);\
    GLLB(2, Bd, kt); GLLB(3, Bd, kt);                                  \
  } while (0)

  f16x8 af[2][8], bf[2][4];
#define READ_K(kk2, Ac, Bc)                                                    \
  do {                                                                         \
    const int off = (((kk2) * 4 + q) ^ x7) * 8;                                \
    _Pragma("unroll")                                                          \
    for (int mi = 0; mi < 8; mi++)                                             \
      af[kk2][mi] =                                                            \
          *(const f16x8*)&(Ac)[(wm * 128 + mi * 16 + lr) * 64 + off];          \
    _Pragma("unroll")                                                          \
    for (int nj = 0; nj < 4; nj++)                                             \
      bf[kk2][nj] = *(const f16x8*)&(Bc)[(wn * 64 + nj * 16 + lr) * 64 + off]; \
  } while (0)

#define MFMA_K(kk2)                                                            \
  do {                                                                         \
    __builtin_amdgcn_s_setprio(1);                                             \
    _Pragma("unroll")                                                          \
    for (int mi = 0; mi < 8; mi++)                                             \
      _Pragma("unroll")                                                        \
      for (int nj = 0; nj < 4; nj++)                                           \
        acc[mi][nj] = __builtin_amdgcn_mfma_f32_16x16x32_f16(                  \
            af[kk2][mi], bf[kk2][nj], acc[mi][nj], 0, 0, 0);                   \
    __builtin_amdgcn_s_setprio(0);                                             \
  } while (0)

  // prologue: stage tiles 0 and 1; wait tile 0 (keep tile 1's 12 in flight)
  STAGE_H1(A0p, B0p, 0);
  STAGE_H2(A0p, B0p, 0);
  STAGE_H1(A1p, B1p, 64);
  STAGE_H2(A1p, B1p, 64);
  __builtin_amdgcn_sched_barrier(0);
  asm volatile("s_waitcnt vmcnt(12)" ::: "memory");
  __builtin_amdgcn_s_barrier();
  __builtin_amdgcn_sched_barrier(0);

  short* cA = A0p; short* nA = A1p; short* sA = A2p;
  short* cB = B0p; short* nB = B1p; short* sB = B2p;

  // steady loop: compute tile t, stage tile t+2, one barrier per tile.
  // End-of-tile wait vmcnt(12): drains t+1's 12 (oldest), keeps t+2's 12.
  for (int t = 0; t < NT - 2; ++t) {
    const int kt2 = (t + 2) * 64;
    READ_K(0, cA, cB);
    STAGE_H1(sA, sB, kt2);
    MFMA_K(0);
    READ_K(1, cA, cB);
    STAGE_H2(sA, sB, kt2);
    MFMA_K(1);
    __builtin_amdgcn_sched_barrier(0);
    asm volatile("s_waitcnt vmcnt(12)" ::: "memory");
    __builtin_amdgcn_s_barrier();
    __builtin_amdgcn_sched_barrier(0);
    short* tp;
    tp = cA; cA = nA; nA = sA; sA = tp;
    tp = cB; cB = nB; nB = sB; sB = tp;
  }

  // t = NT-2: no staging; drain tile NT-1's loads fully
  READ_K(0, cA, cB);
  MFMA_K(0);
  READ_K(1, cA, cB);
  MFMA_K(1);
  __builtin_amdgcn_sched_barrier(0);
  asm volatile("s_waitcnt vmcnt(0)" ::: "memory");
  __builtin_amdgcn_s_barrier();
  __builtin_amdgcn_sched_barrier(0);
  cA = nA; cB = nB;

  // t = NT-1: final tile
  READ_K(0, cA, cB);
  MFMA_K(0);
  READ_K(1, cA, cB);
  MFMA_K(1);

#undef READ_K
#undef MFMA_K
#undef STAGE_H1
#undef STAGE_H2
#undef GLLA
#undef GLLB

  // C/D layout (m89-verified): col = lane&15, row = (lane>>4)*4 + reg
#pragma unroll
  for (int mi = 0; mi < 8; mi++) {
#pragma unroll
    for (int nj = 0; nj < 4; nj++) {
      const int gcol = n0 + wn * 64 + nj * 16 + lr;
#pragma unroll
      for (int r = 0; r < 4; r++) {
        const int grow = m0 + wm * 128 + mi * 16 + q * 4 + r;
        out[(size_t)grow * D_OUT + gcol] = acc[mi][nj][r];
      }
    }
  }
}

extern "C" void kernel_launch(void* const* d_in, const int* in_sizes, int n_in,
                              void* d_out, int out_size, void* d_ws, size_t ws_size,
                              hipStream_t stream) {
  const float* x     = (const float*)d_in[0];
  const float* gamma = (const float*)d_in[1];
  const float* beta  = (const float*)d_in[2];
  const float* bw    = (const float*)d_in[3];
  const float* sw    = (const float*)d_in[4];
  float* out = (float*)d_out;

  short* W = (short*)d_ws;                         // 512 * 4608 f16
  short* A = (short*)d_ws + (size_t)D_OUT * KTOT;  // 16384 * 4608 f16

  prep_kernel<<<ROWS / 4 + D_OUT, 256, 0, stream>>>(x, gamma, beta, bw, sw, A, W);
  gemm_kernel<<<256, 256, 0, stream>>>(A, W, out);
}

// Round 12
// 182.965 us; speedup vs baseline: 1.5043x; 1.1728x over previous
//
#include <hip/hip_runtime.h>
#include <stdint.h>
#include <math.h>

// BSRBF-KAN layer, SPLIT pipeline (round 12 = restore round-9 best, 184 us):
// out = relu(LN(x)) @ base_W^T + (bspline+rbf)(LN(x)) @ spline_W^T
//  * prep: wprep + LN + relu + basis -> A f16 (r7-verified, ~42 us,
//    within ~15% of write-BW floor; stores coalesced 1KB/wave).
//  * gemm: r9's counted-vmcnt deep pipeline (71 us measured, 85% of the
//    ~60 us LDS-port floor): BM=256 x BN=128, BK=64, 8 waves (2/SIMD),
//    TRIPLE-buffered A+B (144 KB LDS, 1 block/CU), one s_barrier per
//    K-tile, steady wait vmcnt(6) keeps tile t+2's 6 GLLs in flight.
//    Neighborhood explored and measured worse: r10 A-from-L2 regs (174 us,
//    latency-bound gather), r11 4-wave 128x64 tiles (117 us, 1 wave/SIMD
//    can't hide LDS latency), r2-r6 fused variants (120-180 us, serial
//    LDS budget).  XCD-chunked remap: A panel L2-resident per XCD
//    (FETCH 300 -> 92 MB).
//   ws: [W: 512*4608 f16][A: 16384*4608 f16]

#define D_IN  512
#define D_OUT 512
#define NB    8
#define KTOT  (D_IN + D_IN * NB)   // 4608
#define ROWS  16384
#define NT    (KTOT / 64)          // 72

typedef __attribute__((ext_vector_type(2))) _Float16 f16x2;
typedef __attribute__((ext_vector_type(8))) _Float16 f16x8;
typedef __attribute__((ext_vector_type(4))) float f32x4;

__device__ __forceinline__ short f2h(float f) {
  return (short)__builtin_bit_cast(unsigned short, (_Float16)f);  // RNE
}
__device__ __forceinline__ unsigned pkrtz_u(float a, float b) {
  return __builtin_bit_cast(unsigned, __builtin_amdgcn_cvt_pkrtz(a, b));
}
__device__ __forceinline__ unsigned pkadd_f16(unsigned a, unsigned b) {
  f16x2 x = __builtin_bit_cast(f16x2, a), y = __builtin_bit_cast(f16x2, b);
  f16x2 r = x + y;
  return __builtin_bit_cast(unsigned, r);
}

// ---------------- basis eval: one d -> 8 packed f16 (spline + rbf) -------
// (verified rounds 3-11) Spline: closed-form uniform cubic, knots
// (i-3)*0.6 - 1.5; selection via 14-entry perm-selector LUT.
// RBF cascade: 3 transcendentals; z clamped to [-8,16].
__device__ __forceinline__ void basis_write(float xn, const uint4* lut,
                                            short* dst) {
  const float u = fmaf(xn, 1.66666667f, 5.5f);  // (xn+3.3)/0.6
  const float cf = floorf(u);
  const int c = (int)cf;
  const float t = u - cf;
  const float t2 = t * t, t3 = t2 * t, omt = 1.0f - t;
  const float v0 = t3 * 0.16666667f;
  const float v1 = fmaf(fmaf(fmaf(t, -0.5f, 0.5f), t, 0.5f), t, 0.16666667f);
  const float v2 = fmaf(t3, 0.5f, fmaf(t2, -1.0f, 0.66666667f));
  const float v3 = omt * omt * (omt * 0.16666667f);
  const unsigned va = pkrtz_u(v0, v1);
  const unsigned vb = pkrtz_u(v2, v3);

  float z = fmaf(xn, 2.80261895f, 4.20392842f);
  z = fminf(fmaxf(z, -8.0f), 16.0f);
  const float d3 = z - 3.60336723f;              // 3*DLT
  const float R3 = __builtin_amdgcn_exp2f(-(d3 * d3));
  const float G  = __builtin_amdgcn_exp2f(z * 2.40224482f);  // 2*DLT
  const float Gi = __builtin_amdgcn_rcpf(G);
  const float R4 = R3 * (G * 9.11881966e-4f);    // e^-7
  const float R5 = R4 * (G * 1.23409804e-4f);    // e^-9
  const float R6 = R5 * (G * 1.67017007e-5f);    // e^-11
  const float R7 = R6 * (G * 2.26032941e-6f);    // e^-13
  const float R2 = R3 * (Gi * 148.413159f);      // e^5
  const float R1 = R2 * (Gi * 20.0855369f);      // e^3
  const float R0 = R1 * (Gi * 2.71828183f);      // e^1

  const int idx = (c < -1 ? -1 : (c > 12 ? 12 : c)) + 1;
  const uint4 sel = lut[idx];
  const unsigned w0 = pkadd_f16(__builtin_amdgcn_perm(vb, va, sel.x), pkrtz_u(R0, R1));
  const unsigned w1 = pkadd_f16(__builtin_amdgcn_perm(vb, va, sel.y), pkrtz_u(R2, R3));
  const unsigned w2 = pkadd_f16(__builtin_amdgcn_perm(vb, va, sel.z), pkrtz_u(R4, R5));
  const unsigned w3 = pkadd_f16(__builtin_amdgcn_perm(vb, va, sel.w), pkrtz_u(R6, R7));
  const uint4 v4 = {w0, w1, w2, w3};
  *(uint4*)dst = v4;  // 16B store (coalesced 1KB/wave across lanes)
}

// ---------------- prep: wprep + LN + relu + basis -> A[ROWS][KTOT] -------
__global__ __launch_bounds__(256) void prep_kernel(
    const float* __restrict__ x, const float* __restrict__ gamma,
    const float* __restrict__ beta, const float* __restrict__ bw,
    const float* __restrict__ sw, short* __restrict__ A,
    short* __restrict__ W) {
  if (blockIdx.x >= ROWS / 4) {
    const int o = blockIdx.x - ROWS / 4;
    for (int k = threadIdx.x; k < KTOT; k += 256) {
      const float v = (k < D_IN) ? bw[o * D_IN + k]
                                 : sw[(size_t)o * (D_IN * NB) + (k - D_IN)];
      W[(size_t)o * KTOT + k] = f2h(v);
    }
    return;
  }
  __shared__ uint4 LUT[14];
  const int tid = threadIdx.x;
  if (tid < 14) {
    const int cc = tid - 1;
    unsigned e[4];
#pragma unroll
    for (int h = 0; h < 4; ++h) {
      const int m = cc - 2 * h, m2 = m - 1;
      const unsigned lo =
          (m >= 0 && m <= 3) ? (unsigned)((2 * m) | ((2 * m + 1) << 8)) : 0x0C0Cu;
      const unsigned hi =
          (m2 >= 0 && m2 <= 3) ? (unsigned)((2 * m2) | ((2 * m2 + 1) << 8)) : 0x0C0Cu;
      e[h] = lo | (hi << 16);
    }
    const uint4 ev = {e[0], e[1], e[2], e[3]};
    LUT[tid] = ev;
  }
  __syncthreads();

  const int lane = tid & 63, wave = tid >> 6;
  const int row = blockIdx.x * 4 + wave;
  const float* xr = x + (size_t)row * D_IN;

  float xv[8];
  float s = 0.0f, ss = 0.0f;
#pragma unroll
  for (int e = 0; e < 8; e++) {
    xv[e] = xr[e * 64 + lane];
    s += xv[e];
    ss += xv[e] * xv[e];
  }
#pragma unroll
  for (int off = 32; off > 0; off >>= 1) {
    s += __shfl_xor(s, off);
    ss += __shfl_xor(ss, off);
  }
  const float mu = s * (1.0f / D_IN);
  const float var = ss * (1.0f / D_IN) - mu * mu;
  const float rstd = 1.0f / sqrtf(var + 1e-5f);

  short* Ar = A + (size_t)row * KTOT;
#pragma unroll
  for (int e = 0; e < 8; e++) {
    const int d = e * 64 + lane;
    const float xn = fmaf((xv[e] - mu) * rstd, gamma[d], beta[d]);
    Ar[d] = f2h(fmaxf(xn, 0.0f));
    basis_write(xn, LUT, &Ar[D_IN + d * NB]);
  }
}

// ---------------- f16 MFMA GEMM: counted-vmcnt triple-buffer pipeline ----
#define GLL(g, l)                                               \
  __builtin_amdgcn_global_load_lds(                             \
      (const __attribute__((address_space(1))) void*)(g),       \
      (__attribute__((address_space(3))) void*)(l), 16, 0, 0)

__global__ __launch_bounds__(512, 1) void gemm_kernel(
    const short* __restrict__ A, const short* __restrict__ W,
    float* __restrict__ out) {
  __shared__ short Ab[3 * 256 * 64];  // 96 KB, A triple-buffer
  __shared__ short Bb[3 * 128 * 64];  // 48 KB, B triple-buffer
  const int tid = threadIdx.x;                 // 512
  const int lane = tid & 63, wave = tid >> 6;  // 8 waves

  // XCD-chunked remap (bijective, 256 = 8*32): XCD x runs wg in [32x, 32x+32)
  // = m-panels 8x..8x+7, each with its 4 n-blocks -> A panel read by ONE XCD.
  const int b = blockIdx.x;
  const int wg = (b & 7) * 32 + (b >> 3);
  const int m0 = (wg >> 2) * 256;
  const int n0 = (wg & 3) * 128;
  const int wm = wave >> 1, wn = wave & 1;  // per-wave 64x64 output

  const f32x4 zero = {0.0f, 0.0f, 0.0f, 0.0f};
  f32x4 acc[4][4];
#pragma unroll
  for (int i = 0; i < 4; i++)
#pragma unroll
    for (int j = 0; j < 4; j++) acc[i][j] = zero;

  // staging map (R7-verified): thread -> (row r0 = tid>>3 in 0..63,
  // chunk-slot c0 = tid&7); calls add +64 rows; src chunk = c0 ^ (r0&7).
  // Coalesced: 8 threads/row read 8 consecutive 16B chunks (128B segments).
  const int r0 = tid >> 3;
  const int c0 = tid & 7;
  const int qsrc = c0 ^ (r0 & 7);
  const short* gA = A + (size_t)(m0 + r0) * KTOT + qsrc * 8;
  const short* gB = W + (size_t)(n0 + r0) * KTOT + qsrc * 8;
  const int lbase = wave * 512;  // wave-uniform dest base; HW adds lane*16B

  const int lr = lane & 15;
  const int q = lane >> 4;
  const int x7 = lr & 7;

  short* A0p = Ab;  short* A1p = Ab + 16384;  short* A2p = Ab + 32768;
  short* B0p = Bb;  short* B1p = Bb + 8192;   short* B2p = Bb + 16384;

  // 6 GLLs per tile: A rows 0..255 (4 calls), B rows 0..127 (2 calls)
#define STAGE_A01(Ad, Bd, kt)                                          \
  do {                                                                 \
    GLL(gA + (kt), (Ad) + lbase);                                      \
    GLL(gA + (size_t)64 * KTOT + (kt), (Ad) + 4096 + lbase);           \
    GLL(gB + (kt), (Bd) + lbase);                                      \
  } while (0)
#define STAGE_A23(Ad, Bd, kt)                                          \
  do {                                                                 \
    GLL(gA + (size_t)128 * KTOT + (kt), (Ad) + 8192 + lbase);          \
    GLL(gA + (size_t)192 * KTOT + (kt), (Ad) + 12288 + lbase);         \
    GLL(gB + (size_t)64 * KTOT + (kt), (Bd) + 4096 + lbase);           \
  } while (0)

  f16x8 af[2][4], bf[2][4];
#define READ_K(kk2, Ac, Bc)                                                    \
  do {                                                                         \
    const int off = (((kk2) * 4 + q) ^ x7) * 8;                                \
    _Pragma("unroll")                                                          \
    for (int mi = 0; mi < 4; mi++)                                             \
      af[kk2][mi] = *(const f16x8*)&(Ac)[(wm * 64 + mi * 16 + lr) * 64 + off]; \
    _Pragma("unroll")                                                          \
    for (int nj = 0; nj < 4; nj++)                                             \
      bf[kk2][nj] = *(const f16x8*)&(Bc)[(wn * 64 + nj * 16 + lr) * 64 + off]; \
  } while (0)

#define MFMA_K(kk2)                                                            \
  do {                                                                         \
    __builtin_amdgcn_s_setprio(1);                                             \
    _Pragma("unroll")                                                          \
    for (int mi = 0; mi < 4; mi++)                                             \
      _Pragma("unroll")                                                        \
      for (int nj = 0; nj < 4; nj++)                                           \
        acc[mi][nj] = __builtin_amdgcn_mfma_f32_16x16x32_f16(                  \
            af[kk2][mi], bf[kk2][nj], acc[mi][nj], 0, 0, 0);                   \
    __builtin_amdgcn_s_setprio(0);                                             \
  } while (0)

  // prologue: stage tiles 0 and 1; wait tile 0 (keep tile 1's 6 in flight)
  STAGE_A01(A0p, B0p, 0);
  STAGE_A23(A0p, B0p, 0);
  STAGE_A01(A1p, B1p, 64);
  STAGE_A23(A1p, B1p, 64);
  __builtin_amdgcn_sched_barrier(0);
  asm volatile("s_waitcnt vmcnt(6)" ::: "memory");
  __builtin_amdgcn_s_barrier();
  __builtin_amdgcn_sched_barrier(0);

  short* cA = A0p; short* nA = A1p; short* sA = A2p;
  short* cB = B0p; short* nB = B1p; short* sB = B2p;

  // steady loop: compute tile t, stage tile t+2, one barrier per tile.
  // End-of-tile wait vmcnt(6): drains t+1's 6 (oldest), keeps t+2's 6.
  for (int t = 0; t < NT - 2; ++t) {
    const int kt2 = (t + 2) * 64;
    READ_K(0, cA, cB);
    STAGE_A01(sA, sB, kt2);
    MFMA_K(0);
    READ_K(1, cA, cB);
    STAGE_A23(sA, sB, kt2);
    MFMA_K(1);
    __builtin_amdgcn_sched_barrier(0);
    asm volatile("s_waitcnt vmcnt(6)" ::: "memory");
    __builtin_amdgcn_s_barrier();
    __builtin_amdgcn_sched_barrier(0);
    short* tp;
    tp = cA; cA = nA; nA = sA; sA = tp;
    tp = cB; cB = nB; nB = sB; sB = tp;
  }

  // t = NT-2: no staging; drain tile NT-1's loads fully
  READ_K(0, cA, cB);
  MFMA_K(0);
  READ_K(1, cA, cB);
  MFMA_K(1);
  __builtin_amdgcn_sched_barrier(0);
  asm volatile("s_waitcnt vmcnt(0)" ::: "memory");
  __builtin_amdgcn_s_barrier();
  __builtin_amdgcn_sched_barrier(0);
  cA = nA; cB = nB;

  // t = NT-1: final tile
  READ_K(0, cA, cB);
  MFMA_K(0);
  READ_K(1, cA, cB);
  MFMA_K(1);

#undef READ_K
#undef MFMA_K
#undef STAGE_A01
#undef STAGE_A23

  // C/D layout (m89-verified): col = lane&15, row = (lane>>4)*4 + reg
#pragma unroll
  for (int mi = 0; mi < 4; mi++) {
#pragma unroll
    for (int nj = 0; nj < 4; nj++) {
      const int gcol = n0 + wn * 64 + nj * 16 + lr;
#pragma unroll
      for (int r = 0; r < 4; r++) {
        const int grow = m0 + wm * 64 + mi * 16 + q * 4 + r;
        out[(size_t)grow * D_OUT + gcol] = acc[mi][nj][r];
      }
    }
  }
}

extern "C" void kernel_launch(void* const* d_in, const int* in_sizes, int n_in,
                              void* d_out, int out_size, void* d_ws, size_t ws_size,
                              hipStream_t stream) {
  const float* x     = (const float*)d_in[0];
  const float* gamma = (const float*)d_in[1];
  const float* beta  = (const float*)d_in[2];
  const float* bw    = (const float*)d_in[3];
  const float* sw    = (const float*)d_in[4];
  float* out = (float*)d_out;

  short* W = (short*)d_ws;                         // 512 * 4608 f16
  short* A = (short*)d_ws + (size_t)D_OUT * KTOT;  // 16384 * 4608 f16

  prep_kernel<<<ROWS / 4 + D_OUT, 256, 0, stream>>>(x, gamma, beta, bw, sw, A, W);
  gemm_kernel<<<256, 512, 0, stream>>>(A, W, out);
}